// Round 10
// baseline (265.060 us; speedup 1.0000x reference)
//
#include <hip/hip_runtime.h>
#include <cmath>

#define NB 64
#define NN 16800
#define KK 1024
#define NT 1024
#define CAP 2048
#define RQ 17  // ceil(NN/NT)

typedef unsigned long long ull;

// Key: 52-bit mantissa of double sigmoid, +1. s in [0.5,1) => exponent fixed,
// mantissa order-isomorphic to score. 0 = below-threshold. Matches float64
// numpy ordering; fp32-conf duplicates give equal keys, broken by idx asc.
__device__ __forceinline__ ull score_key_d(float cf) {
  double s = 1.0 / (1.0 + exp(-(double)cf));
  if (!(s >= 0.5)) return 0ull;
  return ((ull)__double_as_longlong(s) & 0xFFFFFFFFFFFFFull) + 1ull;
}

// Shared double box decode (contract off => one codegen, numpy op order).
__device__ __forceinline__ void decode_box_d(const float* lp, const float* ap,
                                             double& X0, double& Y0,
                                             double& X1, double& Y1,
                                             double& AR) {
#pragma clang fp contract(off)
  double l0 = (double)lp[0], l1 = (double)lp[1];
  double l2 = (double)lp[2], l3 = (double)lp[3];
  double a0 = (double)ap[0], a1 = (double)ap[1];
  double a2 = (double)ap[2], a3 = (double)ap[3];
  double xy0 = a0 + (l0 * 0.1) * a2;
  double xy1 = a1 + (l1 * 0.1) * a3;
  double w = a2 * exp(l2 * 0.2);
  double h = a3 * exp(l3 * 0.2);
  X0 = xy0 - w * 0.5; Y0 = xy1 - h * 0.5;
  X1 = xy0 + w * 0.5; Y1 = xy1 + h * 0.5;
  AR = fmax(X1 - X0, 0.0) * fmax(Y1 - Y0, 0.0);
}

__device__ __forceinline__ bool iou_gt_d(double i0, double i1, double i2,
                                         double i3, double ia, double j0,
                                         double j1, double j2, double j3,
                                         double ja) {
#pragma clang fp contract(off)
  double lt0 = fmax(i0, j0), lt1 = fmax(i1, j1);
  double rb0 = fmin(i2, j2), rb1 = fmin(i3, j3);
  double w0 = fmax(rb0 - lt0, 0.0), w1 = fmax(rb1 - lt1, 0.0);
  double inter = w0 * w1;
  double den = ((ia + ja) - inter) + 1e-9;  // ref op order
  return (inter / den) > 0.3;
}

__device__ __forceinline__ float rdlanef(float v, int l) {
  return __uint_as_float(__builtin_amdgcn_readlane(__float_as_uint(v), l));
}

// 64-bit readlane: 2x v_readlane_b32 -> SGPR pair (fast, no LDS pipe)
__device__ __forceinline__ ull readlane64(ull v, int l) {
  unsigned int lo = __builtin_amdgcn_readlane((unsigned int)v, l);
  unsigned int hi = __builtin_amdgcn_readlane((unsigned int)(v >> 32), l);
  return ((ull)hi << 32) | (ull)lo;
}

// ---- K1: full-GPU key precompute ------------------------------------------
__global__ __launch_bounds__(256) void key_kernel(
    const float* __restrict__ p_conf, ull* __restrict__ keys, int total) {
  int i = blockIdx.x * blockDim.x + threadIdx.x;
  if (i < total) keys[i] = score_key_d(p_conf[i]);
}

// ---- K2: per-image select (early-stop radix) + sort + decode --------------
__global__ __launch_bounds__(1024, 1) void sort_kernel(
    const float* __restrict__ p_loc, const float* __restrict__ anchors,
    const ull* __restrict__ gkeys, unsigned int* __restrict__ sidx_s,
    float* __restrict__ fbox, float* __restrict__ sval) {
  const int b = blockIdx.x;
  const int tid = threadIdx.x;
  const int lane = tid & 63;
  const int wave = tid >> 6;
  const ull* kb = gkeys + (size_t)b * NN;

  __shared__ ull skey[CAP];
  __shared__ unsigned int sidx[CAP];
  __shared__ unsigned int hist[256];
  __shared__ unsigned int scnt, sh_digit, sh_r, sh_c;

  // radix select with early stop: stop when #candidates(key>=prefix) <= CAP
  unsigned int r = KK;
  ull prefix = 0ull, T = 0ull;
  for (int pass = 0; pass < 7; ++pass) {
    const int shift = 48 - pass * 8;
    if (tid < 256) hist[tid] = 0u;
    __syncthreads();
    const ull pm = pass ? ~((1ull << (shift + 8)) - 1ull) : 0ull;
    for (int i = tid; i < NN; i += NT) {
      ull k = kb[i];
      if (k != 0ull && (k & pm) == prefix)
        atomicAdd(&hist[(unsigned int)(k >> shift) & 255u], 1u);
    }
    __syncthreads();
    if (wave == 0) {
      if (lane == 0) { sh_digit = 0u; sh_r = r; sh_c = 0u; }
      unsigned int carry = 0;
      for (int chunk = 3; chunk >= 0; --chunk) {
        const int bin = chunk * 64 + (63 - lane);  // lane0 = highest bin
        unsigned int c = hist[bin];
        unsigned int x = c;
        #pragma unroll
        for (int d = 1; d < 64; d <<= 1) {
          unsigned int y = __shfl_up(x, d);
          if (lane >= d) x += y;
        }
        unsigned int excl = x - c;
        unsigned int S = carry + excl;
        bool hit = (S < r) && (r <= S + c);
        ull bal = __ballot(hit ? 1 : 0);
        if (bal != 0ull) {
          int hl = __ffsll((long long)bal) - 1;
          unsigned int Sf = __shfl(S, hl);
          unsigned int bf = __shfl((unsigned int)bin, hl);
          unsigned int cf = __shfl(c, hl);
          if (lane == 0) { sh_digit = bf; sh_r = r - Sf; sh_c = cf; }
          break;
        }
        carry += __shfl(x, 63);
      }
    }
    __syncthreads();
    prefix |= ((ull)sh_digit << shift);
    r = sh_r;
    const unsigned int cntge = (KK - r) + sh_c;  // #keys >= prefix (low bits 0)
    if (cntge <= CAP || pass == 6) { T = prefix; break; }
  }

  // compact all candidates k >= T (<= CAP of them)
  if (tid == 0) scnt = 0u;
  for (int i = tid; i < CAP; i += NT) { skey[i] = 0ull; sidx[i] = 0xFFFFFFFFu; }
  __syncthreads();
  for (int i = tid; i < NN; i += NT) {
    ull k = kb[i];
    if (k != 0ull && k >= T) {
      unsigned int pos = atomicAdd(&scnt, 1u);
      if (pos < CAP) { skey[pos] = k; sidx[pos] = (unsigned int)i; }
    }
  }
  __syncthreads();

  // bitonic sort 2048 (key desc, idx asc on ties)
  for (unsigned int k2 = 2; k2 <= CAP; k2 <<= 1) {
    for (unsigned int j = k2 >> 1; j > 0; j >>= 1) {
      for (int i = tid; i < CAP; i += NT) {
        int ixj = i ^ (int)j;
        if (ixj > i) {
          bool up = ((i & k2) == 0);
          ull ka = skey[i], kbv = skey[ixj];
          unsigned int ia = sidx[i], ib = sidx[ixj];
          bool a_after_b = (ka < kbv) || (ka == kbv && ia > ib);
          if (a_after_b == up) {
            skey[i] = kbv; skey[ixj] = ka;
            sidx[i] = ib; sidx[ixj] = ia;
          }
        }
      }
      __syncthreads();
    }
  }

  // decode top-K boxes in double, emit fp32 + idx + score
  const ull mykey = skey[tid];
  const unsigned int myidx = sidx[tid];
  double X0 = 0.0, Y0 = 0.0, X1 = 0.0, Y1 = 0.0, AR = 0.0;
  float v = -1.0f;
  if (mykey != 0ull) {
    decode_box_d(p_loc + ((size_t)b * NN + myidx) * 4,
                 anchors + (size_t)myidx * 4, X0, Y0, X1, Y1, AR);
    double s = __longlong_as_double(
        (long long)(0x3FE0000000000000ull | (mykey - 1ull)));
    v = (float)s;
  }
  sidx_s[(size_t)b * KK + tid] = myidx;
  float* fb = fbox + (size_t)b * 5 * KK;
  fb[0 * KK + tid] = (float)X0; fb[1 * KK + tid] = (float)Y0;
  fb[2 * KK + tid] = (float)X1; fb[3 * KK + tid] = (float)Y1;
  fb[4 * KK + tid] = (float)AR;
  sval[(size_t)b * KK + tid] = v;
}

// ---- K3: triangle IoU bitmask, one (rowgroup,colgroup) task per wave ------
// grid = (64 img, 34); block = 256 (4 waves). 34*4 = 136 = #tasks (16+15+..+1).
// Two-phase: HOT loop is pure-fp32 branchless (uncertain rows flagged into a
// scalar bitmask); COLD fix-up loop (single copy, rarely run) double-confirms
// flagged rows. Keeps fp64 blob out of the unrolled body (I-cache + sched).
__global__ __launch_bounds__(256) void pair_kernel(
    const float* __restrict__ p_loc, const float* __restrict__ anchors,
    const unsigned int* __restrict__ sidx_s, const float* __restrict__ fbox,
    const float* __restrict__ sval, ull* __restrict__ maskg) {
  const int img = blockIdx.x;
  const int wave = threadIdx.x >> 6;
  const int lane = threadIdx.x & 63;
  const int t = blockIdx.y * 4 + wave;  // 0..135

  // task -> (rg, cg): t = off(rg) + (cg - rg), off(rg) = sum_{k<rg}(16-k)
  int rg = 0, rem = t;
  while (rem >= 16 - rg) { rem -= 16 - rg; ++rg; }
  const int cg = rg + rem;

  const float* fb = fbox + (size_t)img * 5 * KK;
  const int irow = rg * 64 + lane;   // this lane's row (held for broadcast)
  const int jcol = cg * 64 + lane;   // this lane's column

  float r0 = fb[0 * KK + irow], r1 = fb[1 * KK + irow];
  float r2 = fb[2 * KK + irow], r3 = fb[3 * KK + irow];
  float ra = fb[4 * KK + irow];
  unsigned int ri = sidx_s[(size_t)img * KK + irow];

  const float cj0 = fb[0 * KK + jcol], cj1 = fb[1 * KK + jcol];
  const float cj2 = fb[2 * KK + jcol], cj3 = fb[3 * KK + jcol];
  const float caj = fb[4 * KK + jcol];
  const unsigned int cidx = sidx_s[(size_t)img * KK + jcol];

  unsigned int wlo = 0u, whi = 0u;  // lane rr holds mask word for row rr
  ull uncrows = 0ull;               // scalar: rows with any uncertain lane
  const bool diag = (rg == cg);

#define PAIR_ROW(rr, DIAG)                                                  \
  {                                                                         \
    const float bi0 = rdlanef(r0, rr), bi1 = rdlanef(r1, rr);               \
    const float bi2 = rdlanef(r2, rr), bi3 = rdlanef(r3, rr);               \
    const float ai = rdlanef(ra, rr);                                       \
    float lt0 = fmaxf(bi0, cj0), lt1 = fmaxf(bi1, cj1);                     \
    float q0 = fminf(bi2, cj2), q1 = fminf(bi3, cj3);                       \
    float w0 = fmaxf(q0 - lt0, 0.0f), w1 = fmaxf(q1 - lt1, 0.0f);           \
    float inter = w0 * w1;                                                  \
    float den = ((ai + caj) - inter) + 1e-9f;                               \
    float d = inter - 0.3f * den;                                           \
    bool bit = d > 0.0f;                                                    \
    if (DIAG) bit = bit && (lane > rr);                                     \
    ull m = __ballot(bit ? 1 : 0);                                          \
    bool unc = fabsf(d) <= den * 1e-3f;                                     \
    ull um = __ballot(unc ? 1 : 0);                                         \
    uncrows |= (um != 0ull) ? (1ull << rr) : 0ull;                          \
    const bool mine = (lane == rr);                                         \
    wlo = mine ? (unsigned int)m : wlo;                                     \
    whi = mine ? (unsigned int)(m >> 32) : whi;                             \
  }

  if (diag) {
    #pragma unroll 8
    for (int rr = 0; rr < 64; ++rr) PAIR_ROW(rr, true)
  } else {
    #pragma unroll 8
    for (int rr = 0; rr < 64; ++rr) PAIR_ROW(rr, false)
  }
#undef PAIR_ROW

  // COLD fix-up: double-confirm rows flagged uncertain (decisions identical
  // to inline version; fp32 bit stands for non-uncertain lanes).
  if (__builtin_expect(uncrows != 0ull, 0)) {
    while (uncrows != 0ull) {
      const int rr = __ffsll((long long)uncrows) - 1;
      uncrows &= uncrows - 1ull;
      const float bi0 = rdlanef(r0, rr), bi1 = rdlanef(r1, rr);
      const float bi2 = rdlanef(r2, rr), bi3 = rdlanef(r3, rr);
      const float ai = rdlanef(ra, rr);
      float lt0 = fmaxf(bi0, cj0), lt1 = fmaxf(bi1, cj1);
      float q0 = fminf(bi2, cj2), q1 = fminf(bi3, cj3);
      float w0 = fmaxf(q0 - lt0, 0.0f), w1 = fmaxf(q1 - lt1, 0.0f);
      float inter = w0 * w1;
      float den = ((ai + caj) - inter) + 1e-9f;
      float d = inter - 0.3f * den;
      bool bit = d > 0.0f;
      const bool unc = fabsf(d) <= den * 1e-3f;
      const unsigned int rbi = __builtin_amdgcn_readlane(ri, rr);
      if (unc) {
        double rX0, rY0, rX1, rY1, rAR, qX0, qY0, qX1, qY1, qAR;
        decode_box_d(p_loc + ((size_t)img * NN + rbi) * 4,
                     anchors + (size_t)rbi * 4, rX0, rY0, rX1, rY1, rAR);
        decode_box_d(p_loc + ((size_t)img * NN + cidx) * 4,
                     anchors + (size_t)cidx * 4, qX0, qY0, qX1, qY1, qAR);
        bit = iou_gt_d(rX0, rY0, rX1, rY1, rAR, qX0, qY0, qX1, qY1, qAR);
      }
      if (diag) bit = bit && (lane > rr);
      ull m = __ballot(bit ? 1 : 0);
      const bool mine = (lane == rr);
      wlo = mine ? (unsigned int)m : wlo;
      whi = mine ? (unsigned int)(m >> 32) : whi;
    }
  }

  // lane rr -> word for row (rg*64+rr), column group cg
  maskg[((size_t)img * KK + (size_t)rg * 64 + lane) * 16 + cg] =
      ((ull)whi << 32) | (ull)wlo;
}

// ---- K4: serial resolve from bitmask + output -----------------------------
// Chain scalarized: curw/vm are wave-uniform scalars; v_readlane replaces
// ds_bpermute-based __shfl in the dependent chain (~120cyc -> ~8cyc per keep).
__global__ __launch_bounds__(1024, 1) void resolve_kernel(
    const float* __restrict__ p_landms, const float* __restrict__ anchors,
    const unsigned int* __restrict__ sidx_s, const float* __restrict__ fbox,
    const float* __restrict__ sval, const ull* __restrict__ maskg,
    float* __restrict__ out) {
  const int img = blockIdx.x, tid = threadIdx.x, lane = tid & 63,
            wave = tid >> 6;
  __shared__ ull buf[2][2048];  // 2 x (128 rows x 16 words) = 32 KB
  __shared__ float svbuf[KK];
  __shared__ ull keepw[16];
  const ull* mg = maskg + (size_t)img * KK * 16;

  svbuf[tid] = sval[(size_t)img * KK + tid];
  for (int u = tid; u < 2048; u += NT) buf[0][u] = mg[u];
  __syncthreads();

  ull supw = 0ull;  // wave0: lane L<16 holds suppression word L
  for (int s = 0; s < 8; ++s) {
    const int cur = s & 1;
    if (wave != 0) {
      if (s + 1 < 8) {  // prefetch next 128 rows while wave0 resolves
        const ull* src = mg + (size_t)(s + 1) * 2048;
        for (int u = tid - 64; u < 2048; u += NT - 64) buf[cur ^ 1][u] = src[u];
      }
    } else {
      #pragma unroll
      for (int half = 0; half < 2; ++half) {
        const int g = 2 * s + half;  // global 64-row group
        const ull vm = __ballot(svbuf[g * 64 + lane] >= 0.0f);  // validity
        ull curw = readlane64(supw, g);  // suppression word g (uniform scalar)
        ull km = 0ull;
        #pragma unroll 8
        for (int rr = 0; rr < 64; ++rr) {
          const int rl = half * 64 + rr;
          ull mw = 0ull;
          // words < g never meaningful (lower triangle): mask them
          if (lane < 16 && lane >= g) mw = buf[cur][rl * 16 + lane];
          const bool keep = (((vm >> rr) & 1ull) != 0ull) &&
                            (((curw >> rr) & 1ull) == 0ull);
          if (keep) {  // wave-uniform (scalar condition)
            km |= (1ull << rr);
            supw |= mw;
            curw |= readlane64(mw, g);
          }
        }
        if (lane == 0) keepw[g] = km;
      }
    }
    __syncthreads();
  }

  const bool keep = ((keepw[tid >> 6] >> (tid & 63)) & 1ull) != 0ull;
  float* op = out + ((size_t)img * KK + tid) * 15;
  if (keep) {
    const float* fb = fbox + (size_t)img * 5 * KK;
    op[0] = fb[0 * KK + tid]; op[1] = fb[1 * KK + tid];
    op[2] = fb[2 * KK + tid]; op[3] = fb[3 * KK + tid];
    const unsigned int myidx = sidx_s[(size_t)img * KK + tid];
    const float* pp = p_landms + ((size_t)img * NN + myidx) * 10;
    const float* ap = anchors + (size_t)myidx * 4;
    double a0 = (double)ap[0], a1 = (double)ap[1];
    double a2 = (double)ap[2], a3 = (double)ap[3];
    #pragma unroll
    for (int q = 0; q < 5; ++q) {
      double px = (double)pp[2 * q], py = (double)pp[2 * q + 1];
      op[4 + 2 * q]     = (float)(a0 + (px * 0.1) * a2);
      op[4 + 2 * q + 1] = (float)(a1 + (py * 0.1) * a3);
    }
    op[14] = svbuf[tid];
  } else {
    #pragma unroll
    for (int q = 0; q < 15; ++q) op[q] = 0.0f;
  }
}

// ---- Fallback: R4 monolithic (passed; used only if ws too small) ----------
__global__ __launch_bounds__(1024, 1) void fallback_kernel(
    const float* __restrict__ p_loc, const float* __restrict__ p_conf,
    const float* __restrict__ p_landms, const float* __restrict__ anchors,
    const ull* __restrict__ gkeys, float* __restrict__ out) {
  const int b = blockIdx.x;
  const int tid = threadIdx.x;
  const int lane = tid & 63;
  const int wave = tid >> 6;

  __shared__ ull skey[CAP];
  __shared__ unsigned int sidx[CAP];
  __shared__ float fb0[KK], fb1[KK], fb2[KK], fb3[KK], farr[KK];
  __shared__ float svalf[KK];
  __shared__ ull chunkmask[32][16];
  __shared__ unsigned int keepm[32];
  __shared__ ull supShared[16];
  __shared__ unsigned int hist[256];
  __shared__ unsigned int scnt, sh_digit, sh_r;

  unsigned long long rkey[RQ];
  if (gkeys != nullptr) {
    const ull* kb = gkeys + (size_t)b * NN;
    #pragma unroll
    for (int q = 0; q < RQ; ++q) {
      const int i = tid + q * NT;
      rkey[q] = (i < NN) ? kb[i] : 0ull;
    }
  } else {
    const float* conf = p_conf + (size_t)b * NN;
    #pragma unroll
    for (int q = 0; q < RQ; ++q) {
      const int i = tid + q * NT;
      rkey[q] = (i < NN) ? score_key_d(conf[i]) : 0ull;
    }
  }

  unsigned int r = KK;
  ull prefix = 0ull;
  for (int pass = 0; pass < 7; ++pass) {
    const int shift = 48 - pass * 8;
    if (tid < 256) hist[tid] = 0u;
    __syncthreads();
    const ull pm = (pass == 0) ? 0ull : ~((1ull << (shift + 8)) - 1ull);
    #pragma unroll
    for (int q = 0; q < RQ; ++q) {
      const int i = tid + q * NT;
      if (i < NN) {
        ull k = rkey[q];
        if (k != 0ull && (k & pm) == prefix)
          atomicAdd(&hist[(unsigned int)(k >> shift) & 255u], 1u);
      }
    }
    __syncthreads();
    if (wave == 0) {
      if (lane == 0) { sh_digit = 0u; sh_r = r; }
      unsigned int carry = 0;
      for (int chunk = 3; chunk >= 0; --chunk) {
        const int bin = chunk * 64 + (63 - lane);
        unsigned int c = hist[bin];
        unsigned int x = c;
        #pragma unroll
        for (int d = 1; d < 64; d <<= 1) {
          unsigned int y = __shfl_up(x, d);
          if (lane >= d) x += y;
        }
        unsigned int excl = x - c;
        unsigned int S = carry + excl;
        bool hit = (S < r) && (r <= S + c);
        ull bal = __ballot(hit ? 1 : 0);
        if (bal != 0ull) {
          int hl = __ffsll((long long)bal) - 1;
          unsigned int Sf = __shfl(S, hl);
          unsigned int bf = __shfl((unsigned int)bin, hl);
          if (lane == 0) { sh_digit = bf; sh_r = r - Sf; }
          break;
        }
        carry += __shfl(x, 63);
      }
    }
    __syncthreads();
    prefix |= ((ull)sh_digit << shift);
    r = sh_r;
    __syncthreads();
  }
  const ull T = prefix;

  if (tid == 0) scnt = 0u;
  for (int i = tid; i < CAP; i += NT) { skey[i] = 0ull; sidx[i] = 0xFFFFFFFFu; }
  __syncthreads();
  #pragma unroll
  for (int q = 0; q < RQ; ++q) {
    const int i = tid + q * NT;
    if (i < NN) {
      ull k = rkey[q];
      if (k != 0ull && k >= T) {
        unsigned int pos = atomicAdd(&scnt, 1u);
        if (pos < CAP) { skey[pos] = k; sidx[pos] = (unsigned int)i; }
      }
    }
  }
  __syncthreads();

  for (unsigned int k2 = 2; k2 <= CAP; k2 <<= 1) {
    for (unsigned int j = k2 >> 1; j > 0; j >>= 1) {
      for (int i = tid; i < CAP; i += NT) {
        int ixj = i ^ (int)j;
        if (ixj > i) {
          bool up = ((i & k2) == 0);
          ull ka = skey[i], kb = skey[ixj];
          unsigned int ia = sidx[i], ib = sidx[ixj];
          bool a_after_b = (ka < kb) || (ka == kb && ia > ib);
          if (a_after_b == up) {
            skey[i] = kb; skey[ixj] = ka;
            sidx[i] = ib; sidx[ixj] = ia;
          }
        }
      }
      __syncthreads();
    }
  }

  const ull mykey = skey[tid];
  const unsigned int myidx = sidx[tid];
  double dX0 = 0.0, dY0 = 0.0, dX1 = 0.0, dY1 = 0.0, dAR = 0.0;
  {
    float v = -1.0f;
    if (mykey != 0ull) {
      decode_box_d(p_loc + ((size_t)b * NN + myidx) * 4,
                   anchors + (size_t)myidx * 4, dX0, dY0, dX1, dY1, dAR);
      double s = __longlong_as_double(
          (long long)(0x3FE0000000000000ull | (mykey - 1ull)));
      v = (float)s;
    }
    fb0[tid] = (float)dX0; fb1[tid] = (float)dY0;
    fb2[tid] = (float)dX1; fb3[tid] = (float)dY1;
    farr[tid] = (float)dAR;
    svalf[tid] = v;
  }
  if (tid < 16) supShared[tid] = 0ull;
  if (tid < 32) keepm[tid] = 0u;
  __syncthreads();

  const float cj0 = fb0[tid], cj1 = fb1[tid], cj2 = fb2[tid], cj3 = fb3[tid];
  const float caj = farr[tid];
  ull supw = 0ull;

  for (int c = 0; c < 32; ++c) {
    for (int rr = 0; rr < 32; ++rr) {
      const int i = c * 32 + rr;
      const bool rowDead =
          (svalf[i] < 0.0f) ||
          (((supShared[i >> 6] >> (i & 63)) & 1ull) != 0ull);
      if (rowDead) continue;
      float bi0 = fb0[i], bi1 = fb1[i], bi2 = fb2[i], bi3 = fb3[i];
      float ai = farr[i];
      float lt0 = fmaxf(bi0, cj0), lt1 = fmaxf(bi1, cj1);
      float q0 = fminf(bi2, cj2), q1 = fminf(bi3, cj3);
      float w0 = fmaxf(q0 - lt0, 0.0f), w1 = fmaxf(q1 - lt1, 0.0f);
      float inter = w0 * w1;
      float den = ((ai + caj) - inter) + 1e-9f;
      float d = inter - 0.3f * den;
      bool bit = d > 0.0f;
      bool unc = fabsf(d) <= den * 1e-3f;
      if (__builtin_expect((bool)__ballot(unc ? 1 : 0), 0)) {
        if (unc) {
          const unsigned int ridx = sidx[i];
          double rX0, rY0, rX1, rY1, rAR;
          decode_box_d(p_loc + ((size_t)b * NN + ridx) * 4,
                       anchors + (size_t)ridx * 4, rX0, rY0, rX1, rY1, rAR);
          bit = iou_gt_d(rX0, rY0, rX1, rY1, rAR, dX0, dY0, dX1, dY1, dAR);
        }
      }
      bit = bit && (tid > i);
      ull m = __ballot(bit ? 1 : 0);
      if (lane == 0) chunkmask[rr][wave] = m;
    }
    __syncthreads();
    if (wave == 0) {
      unsigned int km = 0u;
      for (int rr = 0; rr < 32; ++rr) {
        const int i = c * 32 + rr;
        ull sc = __shfl(supw, i >> 6);
        bool keep = (svalf[i] >= 0.0f) && (((sc >> (i & 63)) & 1ull) == 0ull);
        if (keep) {
          km |= (1u << rr);
          if (lane < 16) supw |= chunkmask[rr][lane];
        }
      }
      if (lane == 0) keepm[c] = km;
      if (lane < 16) supShared[lane] = supw;
    }
    __syncthreads();
  }

  {
    const bool keep = ((keepm[tid >> 5] >> (tid & 31)) & 1u) != 0u;
    float* op = out + ((size_t)b * KK + tid) * 15;
    if (keep) {
      op[0] = fb0[tid]; op[1] = fb1[tid]; op[2] = fb2[tid]; op[3] = fb3[tid];
      const float* pp = p_landms + ((size_t)b * NN + myidx) * 10;
      const float* ap = anchors + (size_t)myidx * 4;
      double a0 = (double)ap[0], a1 = (double)ap[1];
      double a2 = (double)ap[2], a3 = (double)ap[3];
      #pragma unroll
      for (int q = 0; q < 5; ++q) {
        double px = (double)pp[2 * q], py = (double)pp[2 * q + 1];
        op[4 + 2 * q]     = (float)(a0 + (px * 0.1) * a2);
        op[4 + 2 * q + 1] = (float)(a1 + (py * 0.1) * a3);
      }
      op[14] = svalf[tid];
    } else {
      #pragma unroll
      for (int q = 0; q < 15; ++q) op[q] = 0.0f;
    }
  }
}

extern "C" void kernel_launch(void* const* d_in, const int* in_sizes, int n_in,
                              void* d_out, int out_size, void* d_ws, size_t ws_size,
                              hipStream_t stream) {
  const float* p_loc    = (const float*)d_in[0];
  const float* p_conf   = (const float*)d_in[1];
  const float* p_landms = (const float*)d_in[2];
  const float* anchors  = (const float*)d_in[3];
  float* out = (float*)d_out;
  (void)in_sizes; (void)n_in; (void)out_size;

  const size_t keys_bytes = (size_t)NB * NN * sizeof(ull);        // 8,601,600
  const size_t off_sidx = keys_bytes;
  const size_t off_fbox = off_sidx + (size_t)NB * KK * 4;
  const size_t off_sval = off_fbox + (size_t)NB * 5 * KK * 4;
  const size_t off_mask = off_sval + (size_t)NB * KK * 4;
  const size_t mask_bytes = (size_t)NB * KK * 16 * sizeof(ull);   // 8,388,608
  const size_t total = off_mask + mask_bytes;                     // ~18.8 MB

  char* ws = (char*)d_ws;
  const int totalN = NB * NN;

  if (ws_size >= total) {
    ull* keys = (ull*)ws;
    unsigned int* sidx_s = (unsigned int*)(ws + off_sidx);
    float* fbox = (float*)(ws + off_fbox);
    float* sval = (float*)(ws + off_sval);
    ull* maskg = (ull*)(ws + off_mask);

    hipLaunchKernelGGL(key_kernel, dim3((totalN + 255) / 256), dim3(256), 0,
                       stream, p_conf, keys, totalN);
    hipLaunchKernelGGL(sort_kernel, dim3(NB), dim3(NT), 0, stream,
                       p_loc, anchors, keys, sidx_s, fbox, sval);
    hipLaunchKernelGGL(pair_kernel, dim3(NB, 34), dim3(256), 0, stream,
                       p_loc, anchors, sidx_s, fbox, sval, maskg);
    hipLaunchKernelGGL(resolve_kernel, dim3(NB), dim3(NT), 0, stream,
                       p_landms, anchors, sidx_s, fbox, sval, maskg, out);
  } else if (ws_size >= keys_bytes) {
    ull* keys = (ull*)ws;
    hipLaunchKernelGGL(key_kernel, dim3((totalN + 255) / 256), dim3(256), 0,
                       stream, p_conf, keys, totalN);
    hipLaunchKernelGGL(fallback_kernel, dim3(NB), dim3(NT), 0, stream,
                       p_loc, p_conf, p_landms, anchors, keys, out);
  } else {
    hipLaunchKernelGGL(fallback_kernel, dim3(NB), dim3(NT), 0, stream,
                       p_loc, p_conf, p_landms, anchors, (const ull*)nullptr,
                       out);
  }
}

// Round 11
// 228.625 us; speedup vs baseline: 1.1594x; 1.1594x over previous
//
#include <hip/hip_runtime.h>
#include <cmath>

#define NB 64
#define NN 16800
#define KK 1024
#define NT 1024
#define CAP 2048
#define RQ 17  // ceil(NN/NT)

typedef unsigned long long ull;

// Key: 52-bit mantissa of double sigmoid, +1. s in [0.5,1) => exponent fixed,
// mantissa order-isomorphic to score. 0 = below-threshold. Matches float64
// numpy ordering; fp32-conf duplicates give equal keys, broken by idx asc.
__device__ __forceinline__ ull score_key_d(float cf) {
  double s = 1.0 / (1.0 + exp(-(double)cf));
  if (!(s >= 0.5)) return 0ull;
  return ((ull)__double_as_longlong(s) & 0xFFFFFFFFFFFFFull) + 1ull;
}

// Shared double box decode (contract off => one codegen, numpy op order).
__device__ __forceinline__ void decode_box_d(const float* lp, const float* ap,
                                             double& X0, double& Y0,
                                             double& X1, double& Y1,
                                             double& AR) {
#pragma clang fp contract(off)
  double l0 = (double)lp[0], l1 = (double)lp[1];
  double l2 = (double)lp[2], l3 = (double)lp[3];
  double a0 = (double)ap[0], a1 = (double)ap[1];
  double a2 = (double)ap[2], a3 = (double)ap[3];
  double xy0 = a0 + (l0 * 0.1) * a2;
  double xy1 = a1 + (l1 * 0.1) * a3;
  double w = a2 * exp(l2 * 0.2);
  double h = a3 * exp(l3 * 0.2);
  X0 = xy0 - w * 0.5; Y0 = xy1 - h * 0.5;
  X1 = xy0 + w * 0.5; Y1 = xy1 + h * 0.5;
  AR = fmax(X1 - X0, 0.0) * fmax(Y1 - Y0, 0.0);
}

__device__ __forceinline__ bool iou_gt_d(double i0, double i1, double i2,
                                         double i3, double ia, double j0,
                                         double j1, double j2, double j3,
                                         double ja) {
#pragma clang fp contract(off)
  double lt0 = fmax(i0, j0), lt1 = fmax(i1, j1);
  double rb0 = fmin(i2, j2), rb1 = fmin(i3, j3);
  double w0 = fmax(rb0 - lt0, 0.0), w1 = fmax(rb1 - lt1, 0.0);
  double inter = w0 * w1;
  double den = ((ia + ja) - inter) + 1e-9;  // ref op order
  return (inter / den) > 0.3;
}

__device__ __forceinline__ float rdlanef(float v, int l) {
  return __uint_as_float(__builtin_amdgcn_readlane(__float_as_uint(v), l));
}

// 64-bit readlane: 2x v_readlane_b32 -> SGPR pair (fast, no LDS pipe)
__device__ __forceinline__ ull readlane64(ull v, int l) {
  unsigned int lo = __builtin_amdgcn_readlane((unsigned int)v, l);
  unsigned int hi = __builtin_amdgcn_readlane((unsigned int)(v >> 32), l);
  return ((ull)hi << 32) | (ull)lo;
}

// ---- K1: full-GPU key precompute ------------------------------------------
__global__ __launch_bounds__(256) void key_kernel(
    const float* __restrict__ p_conf, ull* __restrict__ keys, int total) {
  int i = blockIdx.x * blockDim.x + threadIdx.x;
  if (i < total) keys[i] = score_key_d(p_conf[i]);
}

// ---- K2: per-image exact counting sort (fast) / radix+bitonic (fallback) --
__global__ __launch_bounds__(1024, 1) void sort_kernel(
    const float* __restrict__ p_loc, const float* __restrict__ anchors,
    const ull* __restrict__ gkeys, unsigned int* __restrict__ sidx_s,
    float* __restrict__ fbox, float* __restrict__ sval) {
  const int b = blockIdx.x;
  const int tid = threadIdx.x;
  const int lane = tid & 63;
  const int wave = tid >> 6;
  const ull* kb = gkeys + (size_t)b * NN;

  __shared__ ull skey[CAP];            // 16 KB (dest / fallback arrays)
  __shared__ unsigned int sidx[CAP];   // 8 KB
  __shared__ unsigned int hist[4096];  // 16 KB (12-bit bins; [0..256) reused by fallback)
  __shared__ unsigned int base[4096];  // 16 KB (bin base ranks, mutated by scatter)
  __shared__ unsigned int totals[64], chcarry[64];
  __shared__ unsigned int sh_found, sh_binT, sh_cB;
  __shared__ unsigned int scnt, sh_digit, sh_r, sh_c;

  // ---------- FAST PATH: 12-bit counting sort ----------
  for (int i = tid; i < 4096; i += NT) hist[i] = 0u;
  if (tid == 0) sh_found = 0u;
  __syncthreads();
  for (int i = tid; i < NN; i += NT) {
    ull k = kb[i];
    if (k != 0ull) {
      unsigned int bin = (unsigned int)(k >> 40);
      if (bin > 4095u) bin = 4095u;  // key==2^52 edge; in-bin sort keeps exact
      atomicAdd(&hist[bin], 1u);
    }
  }
  __syncthreads();
  // pass1: within-chunk inclusive scans from the high end (lane0 = high bin)
  for (int chunk = wave; chunk < 64; chunk += 16) {
    const int bin = chunk * 64 + (63 - lane);
    unsigned int c0 = hist[bin];
    unsigned int x = c0;
    #pragma unroll
    for (int d = 1; d < 64; d <<= 1) {
      unsigned int y = __shfl_up(x, d);
      if (lane >= d) x += y;
    }
    base[bin] = x;  // inclusive count of bins >= bin within chunk
    if (lane == 63) totals[chunk] = x;
  }
  __syncthreads();
  // chunk-level exclusive suffix (sum of strictly higher chunks)
  if (wave == 0) {
    const int chunk = 63 - lane;  // lane0 = highest chunk
    unsigned int t0 = totals[chunk];
    unsigned int x = t0;
    #pragma unroll
    for (int d = 1; d < 64; d <<= 1) {
      unsigned int y = __shfl_up(x, d);
      if (lane >= d) x += y;
    }
    chcarry[chunk] = x - t0;
  }
  __syncthreads();
  // pass2: finalize exact base ranks, detect the rank-1024 crossing bin
  for (int chunk = wave; chunk < 64; chunk += 16) {
    const int bin = chunk * 64 + (63 - lane);
    unsigned int c0 = hist[bin];
    unsigned int S = chcarry[chunk] + base[bin] - c0;  // strictly-higher total
    base[bin] = S;
    if (S < (unsigned)KK && (unsigned)KK <= S + c0) {
      sh_found = 1u; sh_binT = (unsigned int)bin; sh_cB = c0;
    }
  }
  __syncthreads();
  const bool fastOK = (sh_found != 0u) && (sh_cB <= 64u);
  const unsigned int binT = sh_binT;

  if (fastOK) {
    for (int i = tid; i < KK + 64; i += NT) { skey[i] = 0ull; sidx[i] = 0xFFFFFFFFu; }
    __syncthreads();
    // scatter: candidates in bins >= binT land at exact rank + arrival offset
    for (int i = tid; i < NN; i += NT) {
      ull k = kb[i];
      if (k != 0ull) {
        unsigned int bin = (unsigned int)(k >> 40);
        if (bin > 4095u) bin = 4095u;
        if (bin >= binT) {
          unsigned int pos = atomicAdd(&base[bin], 1u);
          if (pos < (unsigned)(KK + 64)) { skey[pos] = k; sidx[pos] = (unsigned int)i; }
        }
      }
    }
    __syncthreads();
    // in-bin cleanup: sort each bin slice by (key desc, idx asc); disjoint
    for (int bin = (int)binT + tid; bin < 4096; bin += NT) {
      unsigned int cnt = hist[bin];
      if (cnt >= 2u) {
        int hi2 = (int)base[bin];       // orig + cnt after scatter
        int lo2 = hi2 - (int)cnt;
        for (int m2 = lo2 + 1; m2 < hi2; ++m2) {
          ull kx = skey[m2]; unsigned int ix = sidx[m2];
          int n2 = m2;
          while (n2 > lo2) {
            ull kp = skey[n2 - 1]; unsigned int ip = sidx[n2 - 1];
            bool after = (kp < kx) || (kp == kx && ip > ix);
            if (!after) break;
            skey[n2] = kp; sidx[n2] = ip; --n2;
          }
          skey[n2] = kx; sidx[n2] = ix;
        }
      }
    }
    __syncthreads();
  } else {
    // ---------- FALLBACK: old radix-select + bitonic-2048 (verbatim) ------
    unsigned int r = KK;
    ull prefix = 0ull, T = 0ull;
    for (int pass = 0; pass < 7; ++pass) {
      const int shift = 48 - pass * 8;
      if (tid < 256) hist[tid] = 0u;
      __syncthreads();
      const ull pm = pass ? ~((1ull << (shift + 8)) - 1ull) : 0ull;
      for (int i = tid; i < NN; i += NT) {
        ull k = kb[i];
        if (k != 0ull && (k & pm) == prefix)
          atomicAdd(&hist[(unsigned int)(k >> shift) & 255u], 1u);
      }
      __syncthreads();
      if (wave == 0) {
        if (lane == 0) { sh_digit = 0u; sh_r = r; sh_c = 0u; }
        unsigned int carry = 0;
        for (int chunk = 3; chunk >= 0; --chunk) {
          const int bin = chunk * 64 + (63 - lane);
          unsigned int c = hist[bin];
          unsigned int x = c;
          #pragma unroll
          for (int d = 1; d < 64; d <<= 1) {
            unsigned int y = __shfl_up(x, d);
            if (lane >= d) x += y;
          }
          unsigned int excl = x - c;
          unsigned int S = carry + excl;
          bool hit = (S < r) && (r <= S + c);
          ull bal = __ballot(hit ? 1 : 0);
          if (bal != 0ull) {
            int hl = __ffsll((long long)bal) - 1;
            unsigned int Sf = __shfl(S, hl);
            unsigned int bf = __shfl((unsigned int)bin, hl);
            unsigned int cf = __shfl(c, hl);
            if (lane == 0) { sh_digit = bf; sh_r = r - Sf; sh_c = cf; }
            break;
          }
          carry += __shfl(x, 63);
        }
      }
      __syncthreads();
      prefix |= ((ull)sh_digit << shift);
      r = sh_r;
      const unsigned int cntge = (KK - r) + sh_c;
      if (cntge <= CAP || pass == 6) { T = prefix; break; }
    }

    if (tid == 0) scnt = 0u;
    for (int i = tid; i < CAP; i += NT) { skey[i] = 0ull; sidx[i] = 0xFFFFFFFFu; }
    __syncthreads();
    for (int i = tid; i < NN; i += NT) {
      ull k = kb[i];
      if (k != 0ull && k >= T) {
        unsigned int pos = atomicAdd(&scnt, 1u);
        if (pos < CAP) { skey[pos] = k; sidx[pos] = (unsigned int)i; }
      }
    }
    __syncthreads();

    for (unsigned int k2 = 2; k2 <= CAP; k2 <<= 1) {
      for (unsigned int j = k2 >> 1; j > 0; j >>= 1) {
        for (int i = tid; i < CAP; i += NT) {
          int ixj = i ^ (int)j;
          if (ixj > i) {
            bool up = ((i & k2) == 0);
            ull ka = skey[i], kbv = skey[ixj];
            unsigned int ia = sidx[i], ib = sidx[ixj];
            bool a_after_b = (ka < kbv) || (ka == kbv && ia > ib);
            if (a_after_b == up) {
              skey[i] = kbv; skey[ixj] = ka;
              sidx[i] = ib; sidx[ixj] = ia;
            }
          }
        }
        __syncthreads();
      }
    }
  }

  // ---------- decode top-K boxes in double, emit fp32 + idx + score --------
  const ull mykey = skey[tid];
  const unsigned int myidx = sidx[tid];
  double X0 = 0.0, Y0 = 0.0, X1 = 0.0, Y1 = 0.0, AR = 0.0;
  float v = -1.0f;
  if (mykey != 0ull) {
    decode_box_d(p_loc + ((size_t)b * NN + myidx) * 4,
                 anchors + (size_t)myidx * 4, X0, Y0, X1, Y1, AR);
    double s = __longlong_as_double(
        (long long)(0x3FE0000000000000ull | (mykey - 1ull)));
    v = (float)s;
  }
  sidx_s[(size_t)b * KK + tid] = myidx;
  float* fb = fbox + (size_t)b * 5 * KK;
  fb[0 * KK + tid] = (float)X0; fb[1 * KK + tid] = (float)Y0;
  fb[2 * KK + tid] = (float)X1; fb[3 * KK + tid] = (float)Y1;
  fb[4 * KK + tid] = (float)AR;
  sval[(size_t)b * KK + tid] = v;
}

// ---- K3: triangle IoU bitmask, one (rowgroup,colgroup) task per wave ------
// grid = (64 img, 34); block = 256 (4 waves). 34*4 = 136 = #tasks (16+15+..+1).
// R9 version (best measured): branchless unrolled row loop, inline rare
// double-confirm, cndmask word capture, single scatter store.
__global__ __launch_bounds__(256) void pair_kernel(
    const float* __restrict__ p_loc, const float* __restrict__ anchors,
    const unsigned int* __restrict__ sidx_s, const float* __restrict__ fbox,
    const float* __restrict__ sval, ull* __restrict__ maskg) {
  const int img = blockIdx.x;
  const int wave = threadIdx.x >> 6;
  const int lane = threadIdx.x & 63;
  const int t = blockIdx.y * 4 + wave;  // 0..135

  int rg = 0, rem = t;
  while (rem >= 16 - rg) { rem -= 16 - rg; ++rg; }
  const int cg = rg + rem;

  const float* fb = fbox + (size_t)img * 5 * KK;
  const int irow = rg * 64 + lane;
  const int jcol = cg * 64 + lane;

  float r0 = fb[0 * KK + irow], r1 = fb[1 * KK + irow];
  float r2 = fb[2 * KK + irow], r3 = fb[3 * KK + irow];
  float ra = fb[4 * KK + irow];
  unsigned int ri = sidx_s[(size_t)img * KK + irow];

  const float cj0 = fb[0 * KK + jcol], cj1 = fb[1 * KK + jcol];
  const float cj2 = fb[2 * KK + jcol], cj3 = fb[3 * KK + jcol];
  const float caj = fb[4 * KK + jcol];
  const unsigned int cidx = sidx_s[(size_t)img * KK + jcol];

  unsigned int wlo = 0u, whi = 0u;  // lane rr holds mask word for row rr

  #pragma unroll 8
  for (int rr = 0; rr < 64; ++rr) {
    const float bi0 = rdlanef(r0, rr), bi1 = rdlanef(r1, rr);
    const float bi2 = rdlanef(r2, rr), bi3 = rdlanef(r3, rr);
    const float ai = rdlanef(ra, rr);
    float lt0 = fmaxf(bi0, cj0), lt1 = fmaxf(bi1, cj1);
    float q0 = fminf(bi2, cj2), q1 = fminf(bi3, cj3);
    float w0 = fmaxf(q0 - lt0, 0.0f), w1 = fmaxf(q1 - lt1, 0.0f);
    float inter = w0 * w1;
    float den = ((ai + caj) - inter) + 1e-9f;
    float d = inter - 0.3f * den;     // sign(d) = sign(iou - 0.3)
    bool bit = d > 0.0f;
    bool unc = fabsf(d) <= den * 1e-3f;  // fp32 iou err ~1e-5 << 1e-3
    if (__builtin_expect((bool)__ballot(unc ? 1 : 0), 0)) {
      const unsigned int rbi = __builtin_amdgcn_readlane(ri, rr);
      if (unc) {
        double rX0, rY0, rX1, rY1, rAR, qX0, qY0, qX1, qY1, qAR;
        decode_box_d(p_loc + ((size_t)img * NN + rbi) * 4,
                     anchors + (size_t)rbi * 4, rX0, rY0, rX1, rY1, rAR);
        decode_box_d(p_loc + ((size_t)img * NN + cidx) * 4,
                     anchors + (size_t)cidx * 4, qX0, qY0, qX1, qY1, qAR);
        bit = iou_gt_d(rX0, rY0, rX1, rY1, rAR, qX0, qY0, qX1, qY1, qAR);
      }
    }
    bit = bit && (jcol > rg * 64 + rr);  // j > i
    ull m = __ballot(bit ? 1 : 0);
    const bool mine = (lane == rr);
    wlo = mine ? (unsigned int)m : wlo;
    whi = mine ? (unsigned int)(m >> 32) : whi;
  }

  maskg[((size_t)img * KK + (size_t)rg * 64 + lane) * 16 + cg] =
      ((ull)whi << 32) | (ull)wlo;
}

// ---- K4: serial resolve from bitmask + output -----------------------------
// Scalarized chain (v_readlane); prefetch loads only upper-triangle words.
__global__ __launch_bounds__(1024, 1) void resolve_kernel(
    const float* __restrict__ p_landms, const float* __restrict__ anchors,
    const unsigned int* __restrict__ sidx_s, const float* __restrict__ fbox,
    const float* __restrict__ sval, const ull* __restrict__ maskg,
    float* __restrict__ out) {
  const int img = blockIdx.x, tid = threadIdx.x, lane = tid & 63,
            wave = tid >> 6;
  __shared__ ull buf[2][2048];  // 2 x (128 rows x 16 words) = 32 KB
  __shared__ float svbuf[KK];
  __shared__ ull keepw[16];
  const ull* mg = maskg + (size_t)img * KK * 16;

  svbuf[tid] = sval[(size_t)img * KK + tid];
  for (int u = tid; u < 2048; u += NT) buf[0][u] = mg[u];
  __syncthreads();

  ull supw = 0ull;  // wave0: lane L<16 holds suppression word L
  for (int s = 0; s < 8; ++s) {
    const int cur = s & 1;
    if (wave != 0) {
      if (s + 1 < 8) {  // prefetch next 128 rows; only words >= 2(s+1) needed
        const ull* src = mg + (size_t)(s + 1) * 2048;
        const int wmin = 2 * (s + 1);
        for (int u = tid - 64; u < 2048; u += NT - 64)
          if ((u & 15) >= wmin) buf[cur ^ 1][u] = src[u];
      }
    } else {
      #pragma unroll
      for (int half = 0; half < 2; ++half) {
        const int g = 2 * s + half;  // global 64-row group
        const ull vm = __ballot(svbuf[g * 64 + lane] >= 0.0f);  // validity
        ull curw = readlane64(supw, g);
        ull km = 0ull;
        #pragma unroll 8
        for (int rr = 0; rr < 64; ++rr) {
          const int rl = half * 64 + rr;
          ull mw = 0ull;
          if (lane < 16 && lane >= g) mw = buf[cur][rl * 16 + lane];
          const bool keep = (((vm >> rr) & 1ull) != 0ull) &&
                            (((curw >> rr) & 1ull) == 0ull);
          if (keep) {
            km |= (1ull << rr);
            supw |= mw;
            curw |= readlane64(mw, g);
          }
        }
        if (lane == 0) keepw[g] = km;
      }
    }
    __syncthreads();
  }

  const bool keep = ((keepw[tid >> 6] >> (tid & 63)) & 1ull) != 0ull;
  float* op = out + ((size_t)img * KK + tid) * 15;
  if (keep) {
    const float* fb = fbox + (size_t)img * 5 * KK;
    op[0] = fb[0 * KK + tid]; op[1] = fb[1 * KK + tid];
    op[2] = fb[2 * KK + tid]; op[3] = fb[3 * KK + tid];
    const unsigned int myidx = sidx_s[(size_t)img * KK + tid];
    const float* pp = p_landms + ((size_t)img * NN + myidx) * 10;
    const float* ap = anchors + (size_t)myidx * 4;
    double a0 = (double)ap[0], a1 = (double)ap[1];
    double a2 = (double)ap[2], a3 = (double)ap[3];
    #pragma unroll
    for (int q = 0; q < 5; ++q) {
      double px = (double)pp[2 * q], py = (double)pp[2 * q + 1];
      op[4 + 2 * q]     = (float)(a0 + (px * 0.1) * a2);
      op[4 + 2 * q + 1] = (float)(a1 + (py * 0.1) * a3);
    }
    op[14] = svbuf[tid];
  } else {
    #pragma unroll
    for (int q = 0; q < 15; ++q) op[q] = 0.0f;
  }
}

// ---- Fallback: R4 monolithic (passed; used only if ws too small) ----------
__global__ __launch_bounds__(1024, 1) void fallback_kernel(
    const float* __restrict__ p_loc, const float* __restrict__ p_conf,
    const float* __restrict__ p_landms, const float* __restrict__ anchors,
    const ull* __restrict__ gkeys, float* __restrict__ out) {
  const int b = blockIdx.x;
  const int tid = threadIdx.x;
  const int lane = tid & 63;
  const int wave = tid >> 6;

  __shared__ ull skey[CAP];
  __shared__ unsigned int sidx[CAP];
  __shared__ float fb0[KK], fb1[KK], fb2[KK], fb3[KK], farr[KK];
  __shared__ float svalf[KK];
  __shared__ ull chunkmask[32][16];
  __shared__ unsigned int keepm[32];
  __shared__ ull supShared[16];
  __shared__ unsigned int hist[256];
  __shared__ unsigned int scnt, sh_digit, sh_r;

  unsigned long long rkey[RQ];
  if (gkeys != nullptr) {
    const ull* kb = gkeys + (size_t)b * NN;
    #pragma unroll
    for (int q = 0; q < RQ; ++q) {
      const int i = tid + q * NT;
      rkey[q] = (i < NN) ? kb[i] : 0ull;
    }
  } else {
    const float* conf = p_conf + (size_t)b * NN;
    #pragma unroll
    for (int q = 0; q < RQ; ++q) {
      const int i = tid + q * NT;
      rkey[q] = (i < NN) ? score_key_d(conf[i]) : 0ull;
    }
  }

  unsigned int r = KK;
  ull prefix = 0ull;
  for (int pass = 0; pass < 7; ++pass) {
    const int shift = 48 - pass * 8;
    if (tid < 256) hist[tid] = 0u;
    __syncthreads();
    const ull pm = (pass == 0) ? 0ull : ~((1ull << (shift + 8)) - 1ull);
    #pragma unroll
    for (int q = 0; q < RQ; ++q) {
      const int i = tid + q * NT;
      if (i < NN) {
        ull k = rkey[q];
        if (k != 0ull && (k & pm) == prefix)
          atomicAdd(&hist[(unsigned int)(k >> shift) & 255u], 1u);
      }
    }
    __syncthreads();
    if (wave == 0) {
      if (lane == 0) { sh_digit = 0u; sh_r = r; }
      unsigned int carry = 0;
      for (int chunk = 3; chunk >= 0; --chunk) {
        const int bin = chunk * 64 + (63 - lane);
        unsigned int c = hist[bin];
        unsigned int x = c;
        #pragma unroll
        for (int d = 1; d < 64; d <<= 1) {
          unsigned int y = __shfl_up(x, d);
          if (lane >= d) x += y;
        }
        unsigned int excl = x - c;
        unsigned int S = carry + excl;
        bool hit = (S < r) && (r <= S + c);
        ull bal = __ballot(hit ? 1 : 0);
        if (bal != 0ull) {
          int hl = __ffsll((long long)bal) - 1;
          unsigned int Sf = __shfl(S, hl);
          unsigned int bf = __shfl((unsigned int)bin, hl);
          if (lane == 0) { sh_digit = bf; sh_r = r - Sf; }
          break;
        }
        carry += __shfl(x, 63);
      }
    }
    __syncthreads();
    prefix |= ((ull)sh_digit << shift);
    r = sh_r;
    __syncthreads();
  }
  const ull T = prefix;

  if (tid == 0) scnt = 0u;
  for (int i = tid; i < CAP; i += NT) { skey[i] = 0ull; sidx[i] = 0xFFFFFFFFu; }
  __syncthreads();
  #pragma unroll
  for (int q = 0; q < RQ; ++q) {
    const int i = tid + q * NT;
    if (i < NN) {
      ull k = rkey[q];
      if (k != 0ull && k >= T) {
        unsigned int pos = atomicAdd(&scnt, 1u);
        if (pos < CAP) { skey[pos] = k; sidx[pos] = (unsigned int)i; }
      }
    }
  }
  __syncthreads();

  for (unsigned int k2 = 2; k2 <= CAP; k2 <<= 1) {
    for (unsigned int j = k2 >> 1; j > 0; j >>= 1) {
      for (int i = tid; i < CAP; i += NT) {
        int ixj = i ^ (int)j;
        if (ixj > i) {
          bool up = ((i & k2) == 0);
          ull ka = skey[i], kb = skey[ixj];
          unsigned int ia = sidx[i], ib = sidx[ixj];
          bool a_after_b = (ka < kb) || (ka == kb && ia > ib);
          if (a_after_b == up) {
            skey[i] = kb; skey[ixj] = ka;
            sidx[i] = ib; sidx[ixj] = ia;
          }
        }
      }
      __syncthreads();
    }
  }

  const ull mykey = skey[tid];
  const unsigned int myidx = sidx[tid];
  double dX0 = 0.0, dY0 = 0.0, dX1 = 0.0, dY1 = 0.0, dAR = 0.0;
  {
    float v = -1.0f;
    if (mykey != 0ull) {
      decode_box_d(p_loc + ((size_t)b * NN + myidx) * 4,
                   anchors + (size_t)myidx * 4, dX0, dY0, dX1, dY1, dAR);
      double s = __longlong_as_double(
          (long long)(0x3FE0000000000000ull | (mykey - 1ull)));
      v = (float)s;
    }
    fb0[tid] = (float)dX0; fb1[tid] = (float)dY0;
    fb2[tid] = (float)dX1; fb3[tid] = (float)dY1;
    farr[tid] = (float)dAR;
    svalf[tid] = v;
  }
  if (tid < 16) supShared[tid] = 0ull;
  if (tid < 32) keepm[tid] = 0u;
  __syncthreads();

  const float cj0 = fb0[tid], cj1 = fb1[tid], cj2 = fb2[tid], cj3 = fb3[tid];
  const float caj = farr[tid];
  ull supw = 0ull;

  for (int c = 0; c < 32; ++c) {
    for (int rr = 0; rr < 32; ++rr) {
      const int i = c * 32 + rr;
      const bool rowDead =
          (svalf[i] < 0.0f) ||
          (((supShared[i >> 6] >> (i & 63)) & 1ull) != 0ull);
      if (rowDead) continue;
      float bi0 = fb0[i], bi1 = fb1[i], bi2 = fb2[i], bi3 = fb3[i];
      float ai = farr[i];
      float lt0 = fmaxf(bi0, cj0), lt1 = fmaxf(bi1, cj1);
      float q0 = fminf(bi2, cj2), q1 = fminf(bi3, cj3);
      float w0 = fmaxf(q0 - lt0, 0.0f), w1 = fmaxf(q1 - lt1, 0.0f);
      float inter = w0 * w1;
      float den = ((ai + caj) - inter) + 1e-9f;
      float d = inter - 0.3f * den;
      bool bit = d > 0.0f;
      bool unc = fabsf(d) <= den * 1e-3f;
      if (__builtin_expect((bool)__ballot(unc ? 1 : 0), 0)) {
        if (unc) {
          const unsigned int ridx = sidx[i];
          double rX0, rY0, rX1, rY1, rAR;
          decode_box_d(p_loc + ((size_t)b * NN + ridx) * 4,
                       anchors + (size_t)ridx * 4, rX0, rY0, rX1, rY1, rAR);
          bit = iou_gt_d(rX0, rY0, rX1, rY1, rAR, dX0, dY0, dX1, dY1, dAR);
        }
      }
      bit = bit && (tid > i);
      ull m = __ballot(bit ? 1 : 0);
      if (lane == 0) chunkmask[rr][wave] = m;
    }
    __syncthreads();
    if (wave == 0) {
      unsigned int km = 0u;
      for (int rr = 0; rr < 32; ++rr) {
        const int i = c * 32 + rr;
        ull sc = __shfl(supw, i >> 6);
        bool keep = (svalf[i] >= 0.0f) && (((sc >> (i & 63)) & 1ull) == 0ull);
        if (keep) {
          km |= (1u << rr);
          if (lane < 16) supw |= chunkmask[rr][lane];
        }
      }
      if (lane == 0) keepm[c] = km;
      if (lane < 16) supShared[lane] = supw;
    }
    __syncthreads();
  }

  {
    const bool keep = ((keepm[tid >> 5] >> (tid & 31)) & 1u) != 0u;
    float* op = out + ((size_t)b * KK + tid) * 15;
    if (keep) {
      op[0] = fb0[tid]; op[1] = fb1[tid]; op[2] = fb2[tid]; op[3] = fb3[tid];
      const float* pp = p_landms + ((size_t)b * NN + myidx) * 10;
      const float* ap = anchors + (size_t)myidx * 4;
      double a0 = (double)ap[0], a1 = (double)ap[1];
      double a2 = (double)ap[2], a3 = (double)ap[3];
      #pragma unroll
      for (int q = 0; q < 5; ++q) {
        double px = (double)pp[2 * q], py = (double)pp[2 * q + 1];
        op[4 + 2 * q]     = (float)(a0 + (px * 0.1) * a2);
        op[4 + 2 * q + 1] = (float)(a1 + (py * 0.1) * a3);
      }
      op[14] = svalf[tid];
    } else {
      #pragma unroll
      for (int q = 0; q < 15; ++q) op[q] = 0.0f;
    }
  }
}

extern "C" void kernel_launch(void* const* d_in, const int* in_sizes, int n_in,
                              void* d_out, int out_size, void* d_ws, size_t ws_size,
                              hipStream_t stream) {
  const float* p_loc    = (const float*)d_in[0];
  const float* p_conf   = (const float*)d_in[1];
  const float* p_landms = (const float*)d_in[2];
  const float* anchors  = (const float*)d_in[3];
  float* out = (float*)d_out;
  (void)in_sizes; (void)n_in; (void)out_size;

  const size_t keys_bytes = (size_t)NB * NN * sizeof(ull);        // 8,601,600
  const size_t off_sidx = keys_bytes;
  const size_t off_fbox = off_sidx + (size_t)NB * KK * 4;
  const size_t off_sval = off_fbox + (size_t)NB * 5 * KK * 4;
  const size_t off_mask = off_sval + (size_t)NB * KK * 4;
  const size_t mask_bytes = (size_t)NB * KK * 16 * sizeof(ull);   // 8,388,608
  const size_t total = off_mask + mask_bytes;                     // ~18.8 MB

  char* ws = (char*)d_ws;
  const int totalN = NB * NN;

  if (ws_size >= total) {
    ull* keys = (ull*)ws;
    unsigned int* sidx_s = (unsigned int*)(ws + off_sidx);
    float* fbox = (float*)(ws + off_fbox);
    float* sval = (float*)(ws + off_sval);
    ull* maskg = (ull*)(ws + off_mask);

    hipLaunchKernelGGL(key_kernel, dim3((totalN + 255) / 256), dim3(256), 0,
                       stream, p_conf, keys, totalN);
    hipLaunchKernelGGL(sort_kernel, dim3(NB), dim3(NT), 0, stream,
                       p_loc, anchors, keys, sidx_s, fbox, sval);
    hipLaunchKernelGGL(pair_kernel, dim3(NB, 34), dim3(256), 0, stream,
                       p_loc, anchors, sidx_s, fbox, sval, maskg);
    hipLaunchKernelGGL(resolve_kernel, dim3(NB), dim3(NT), 0, stream,
                       p_landms, anchors, sidx_s, fbox, sval, maskg, out);
  } else if (ws_size >= keys_bytes) {
    ull* keys = (ull*)ws;
    hipLaunchKernelGGL(key_kernel, dim3((totalN + 255) / 256), dim3(256), 0,
                       stream, p_conf, keys, totalN);
    hipLaunchKernelGGL(fallback_kernel, dim3(NB), dim3(NT), 0, stream,
                       p_loc, p_conf, p_landms, anchors, keys, out);
  } else {
    hipLaunchKernelGGL(fallback_kernel, dim3(NB), dim3(NT), 0, stream,
                       p_loc, p_conf, p_landms, anchors, (const ull*)nullptr,
                       out);
  }
}